// Round 1
// baseline (355.363 us; speedup 1.0000x reference)
//
#include <hip/hip_runtime.h>
#include <hip/hip_bf16.h>

// ModulatedConv2d (StyleGAN2): B=16, Cin=Cout=128, K=3, H=W=128, STYLE=512
// Strategy: bf16 MFMA implicit GEMM per (b, y-row). M=cout(128), N=x(128), K=cin*9.
// ws layout: [0, 8KB) s[b][cin] fp32 ; [8KB, ~4.7MB) wmod bf16 [b][9][cout][cin];
//            [8MB, 8MB+68MB) x NHWC bf16 col-padded [b][y][130][cin]. Needs ~76MB ws.

typedef __attribute__((ext_vector_type(8))) short short8;
typedef __attribute__((ext_vector_type(4))) float f32x4;

#define XPITCH (130 * 128)
#define CONV_SCALE 0.029462782549439483f /* 1/sqrt(128*9) */
#define LIN_SCALE 0.04419417382415922f   /* 1/sqrt(512) */

__device__ __forceinline__ void async16(unsigned short* lds, const unsigned short* g) {
  __builtin_amdgcn_global_load_lds((const __attribute__((address_space(1))) void*)g,
                                   (__attribute__((address_space(3))) void*)lds, 16, 0, 0);
}

// s[b][cin] = sum_d style[b,d] * mod_w[cin,d] * LIN_SCALE + mod_b[cin]
__global__ void style_kernel(const float* __restrict__ style, const float* __restrict__ mod_w,
                             const float* __restrict__ mod_b, float* __restrict__ s_ws) {
  const int b = blockIdx.x, c = threadIdx.x;
  __shared__ float st[512];
  for (int i = threadIdx.x; i < 512; i += 128) st[i] = style[b * 512 + i];
  __syncthreads();
  const float* mw = mod_w + (size_t)c * 512;
  float acc = 0.f;
  for (int d = 0; d < 512; ++d) acc += st[d] * mw[d];
  s_ws[b * 128 + c] = acc * LIN_SCALE + mod_b[c];
}

// one block per (b, cout): wmod = CONV_SCALE*weight*s ; demod = rsqrt(sum wmod^2 + 1e-8)
// write bf16 w_ws[b][ky*3+kx][cout][cin]  (cin fastest, for A-tile staging)
__global__ void modw_kernel(const float* __restrict__ weight, const float* __restrict__ s_ws,
                            unsigned short* __restrict__ w_ws) {
  const int bid = blockIdx.x;
  const int b = bid >> 7, cout = bid & 127;
  const int cin = threadIdx.x;
  const float sv = s_ws[b * 128 + cin] * CONV_SCALE;
  const float* wp = weight + ((size_t)cout * 128 + cin) * 9;
  float v[9];
  float ss = 0.f;
#pragma unroll
  for (int j = 0; j < 9; ++j) { v[j] = wp[j] * sv; ss += v[j] * v[j]; }
#pragma unroll
  for (int off = 32; off; off >>= 1) ss += __shfl_down(ss, off);
  __shared__ float red[2];
  if ((threadIdx.x & 63) == 0) red[threadIdx.x >> 6] = ss;
  __syncthreads();
  const float dem = rsqrtf(red[0] + red[1] + 1e-8f);
#pragma unroll
  for (int j = 0; j < 9; ++j) {
    __hip_bfloat16 h = __float2bfloat16(v[j] * dem);
    w_ws[(((size_t)b * 9 + j) * 128 + cout) * 128 + cin] =
        __builtin_bit_cast(unsigned short, h);
  }
}

// x[b][cin][y][x] fp32 -> xp[b][y][xcol 0..129][cin] bf16, xcol = x+1, guards zero.
__global__ void nhwc_kernel(const float* __restrict__ x, unsigned short* __restrict__ xp) {
  const int bid = blockIdx.x;
  const int b = bid >> 7, y = bid & 127;
  const int tid = threadIdx.x;
  const float* xb = x + (size_t)b * 128 * 16384 + y * 128;  // + cin*16384 + xc
  unsigned short* ob = xp + (size_t)(b * 128 + y) * XPITCH;
#pragma unroll
  for (int it = 0; it < 8; ++it) {
    const int v = it * 256 + tid;
    const int g = v >> 7, xc = v & 127;  // cin group (of 8), x coordinate
    short8 pack;
#pragma unroll
    for (int j = 0; j < 8; ++j) {
      __hip_bfloat16 h = __float2bfloat16(xb[(size_t)(g * 8 + j) * 16384 + xc]);
      pack[j] = __builtin_bit_cast(short, h);
    }
    *(short8*)(ob + (xc + 1) * 128 + g * 8) = pack;
  }
  const int c = tid & 127;
  if (tid < 128) ob[c] = 0;           // xcol 0  (x = -1)
  else           ob[129 * 128 + c] = 0;  // xcol 129 (x = 128)
}

// one block per (b, y): out[b][0..127][y][0..127] = sum_{ky,kx,cin} w'*x
// 128x128 tile, 4 waves in 2x2, each wave 4x4 of 16x16x32 bf16 MFMA, BK=64.
__global__ __launch_bounds__(256, 3) void conv_kernel(const unsigned short* __restrict__ xp,
                                                      const unsigned short* __restrict__ wws,
                                                      float* __restrict__ out) {
  __shared__ unsigned short lA[128 * 64];
  __shared__ unsigned short lB[128 * 64];
  const int tid = threadIdx.x;
  const int bid = blockIdx.x;
  const int b = bid >> 7, y = bid & 127;
  const int lane = tid & 63, w = tid >> 6;
  const int wm = w & 1, wn = w >> 1;
  const int l15 = lane & 15, q = lane >> 4;

  f32x4 acc[4][4];
#pragma unroll
  for (int i = 0; i < 4; ++i)
#pragma unroll
    for (int t = 0; t < 4; ++t) acc[i][t] = (f32x4){0.f, 0.f, 0.f, 0.f};

  const unsigned short* xb = xp + (size_t)b * 128 * XPITCH;
  const unsigned short* wb = wws + (size_t)b * 9 * 128 * 128;

  // staging: thread covers LDS bytes p*4096 + tid*16 (lane-linear per wave as required).
  // XOR swizzle applied on the GLOBAL side: physical 16B group g_phys at row m holds
  // logical group g_phys ^ (m&7)  -> breaks 128B-row-stride bank conflicts on ds_read_b128.
  const int mbase = tid >> 3;                              // row within 32-row slab
  const int goff = (((tid & 7) ^ ((tid >> 3) & 7)) << 3);  // logical elem offset of group
  const int eoff = tid * 8;

  for (int j3 = 0; j3 < 9; ++j3) {
    const int ky = j3 / 3;
    const int kx = j3 - ky * 3;
    const int yy = y + ky - 1;
    if (yy < 0 || yy > 127) continue;  // uniform per block: zero-pad rows skipped
    const unsigned short* Ab = wb + j3 * (128 * 128);
    const unsigned short* Bb = xb + yy * XPITCH + kx * 128;  // padded col = p + kx
    for (int c0 = 0; c0 < 128; c0 += 64) {
      __syncthreads();
#pragma unroll
      for (int p = 0; p < 4; ++p) {
        const int gofs = p * 4096 + mbase * 128 + c0 + goff;
        const int e = p * 2048 + eoff;
        async16(lA + e, Ab + gofs);
        async16(lB + e, Bb + gofs);
      }
      __syncthreads();
#pragma unroll
      for (int s = 0; s < 2; ++s) {
        const int axor = (((s * 4 + q) ^ (l15 & 7)) << 3);
        short8 af[4], bf[4];
#pragma unroll
        for (int i = 0; i < 4; ++i)
          af[i] = *(const short8*)(lA + (wm * 64 + i * 16 + l15) * 64 + axor);
#pragma unroll
        for (int t = 0; t < 4; ++t)
          bf[t] = *(const short8*)(lB + (wn * 64 + t * 16 + l15) * 64 + axor);
#pragma unroll
        for (int i = 0; i < 4; ++i)
#pragma unroll
          for (int t = 0; t < 4; ++t)
            acc[i][t] = __builtin_amdgcn_mfma_f32_16x16x32_bf16(af[i], bf[t], acc[i][t], 0, 0, 0);
      }
    }
  }

  // C/D layout: col(pixel) = lane&15, row(cout) = (lane>>4)*4 + reg
  float* ob = out + ((size_t)b * 128 * 128 + y) * 128;
#pragma unroll
  for (int i = 0; i < 4; ++i) {
    const int coutb = wm * 64 + i * 16 + q * 4;
#pragma unroll
    for (int r = 0; r < 4; ++r) {
      float* orow = ob + (size_t)(coutb + r) * (128 * 128);
#pragma unroll
      for (int t = 0; t < 4; ++t) orow[wn * 64 + t * 16 + l15] = acc[i][t][r];
    }
  }
}

extern "C" void kernel_launch(void* const* d_in, const int* in_sizes, int n_in,
                              void* d_out, int out_size, void* d_ws, size_t ws_size,
                              hipStream_t stream) {
  const float* x = (const float*)d_in[0];
  const float* style = (const float*)d_in[1];
  const float* weight = (const float*)d_in[2];
  const float* mod_w = (const float*)d_in[3];
  const float* mod_b = (const float*)d_in[4];
  float* out = (float*)d_out;

  char* ws = (char*)d_ws;
  float* s_ws = (float*)ws;                                   // 8 KB
  unsigned short* w_ws = (unsigned short*)(ws + 8192);        // 4.7 MB
  unsigned short* xp = (unsigned short*)(ws + (8u << 20));    // 68 MB

  style_kernel<<<16, 128, 0, stream>>>(style, mod_w, mod_b, s_ws);
  modw_kernel<<<16 * 128, 128, 0, stream>>>(weight, s_ws, w_ws);
  nhwc_kernel<<<16 * 128, 256, 0, stream>>>(x, xp);
  conv_kernel<<<16 * 128, 256, 0, stream>>>(xp, w_ws, out);
}

// Round 2
// 330.438 us; speedup vs baseline: 1.0754x; 1.0754x over previous
//
#include <hip/hip_runtime.h>
#include <hip/hip_bf16.h>

// ModulatedConv2d (StyleGAN2): B=16, Cin=Cout=128, K=3, H=W=128, STYLE=512
// bf16 MFMA implicit GEMM per (b, y-row). M=cout(128), N=x(128), K=cin*9.
// R2: XCD-aware block swizzle in conv (3x input-row L2 reuse within an XCD),
//     coalesced wave-per-(b,cin) style kernel.

typedef __attribute__((ext_vector_type(8))) short short8;
typedef __attribute__((ext_vector_type(4))) float f32x4;

#define XPITCH (130 * 128)
#define CONV_SCALE 0.029462782549439483f /* 1/sqrt(128*9) */
#define LIN_SCALE 0.04419417382415922f   /* 1/sqrt(512) */

__device__ __forceinline__ void async16(unsigned short* lds, const unsigned short* g) {
  __builtin_amdgcn_global_load_lds((const __attribute__((address_space(1))) void*)g,
                                   (__attribute__((address_space(3))) void*)lds, 16, 0, 0);
}

// s[b][cin] = sum_d style[b,d] * mod_w[cin,d] * LIN_SCALE + mod_b[cin]
// one wave per (b,cin); lanes cover d with float4 (fully coalesced).
__global__ void style_kernel(const float* __restrict__ style, const float* __restrict__ mod_w,
                             const float* __restrict__ mod_b, float* __restrict__ s_ws) {
  const int gw = blockIdx.x * 4 + (threadIdx.x >> 6);  // global wave 0..2047
  const int b = gw >> 7, cin = gw & 127, lane = threadIdx.x & 63;
  const float4 s0 = *(const float4*)(style + (size_t)b * 512 + lane * 4);
  const float4 s1 = *(const float4*)(style + (size_t)b * 512 + 256 + lane * 4);
  const float4 w0 = *(const float4*)(mod_w + (size_t)cin * 512 + lane * 4);
  const float4 w1 = *(const float4*)(mod_w + (size_t)cin * 512 + 256 + lane * 4);
  float acc = s0.x * w0.x + s0.y * w0.y + s0.z * w0.z + s0.w * w0.w +
              s1.x * w1.x + s1.y * w1.y + s1.z * w1.z + s1.w * w1.w;
#pragma unroll
  for (int off = 32; off; off >>= 1) acc += __shfl_xor(acc, off);
  if (lane == 0) s_ws[b * 128 + cin] = acc * LIN_SCALE + mod_b[cin];
}

// one block per (b, cout): wmod = CONV_SCALE*weight*s ; demod = rsqrt(sum wmod^2 + 1e-8)
// write bf16 w_ws[b][ky*3+kx][cout][cin]  (cin fastest, for A-tile staging)
__global__ void modw_kernel(const float* __restrict__ weight, const float* __restrict__ s_ws,
                            unsigned short* __restrict__ w_ws) {
  const int bid = blockIdx.x;
  const int b = bid >> 7, cout = bid & 127;
  const int cin = threadIdx.x;
  const float sv = s_ws[b * 128 + cin] * CONV_SCALE;
  const float* wp = weight + ((size_t)cout * 128 + cin) * 9;
  float v[9];
  float ss = 0.f;
#pragma unroll
  for (int j = 0; j < 9; ++j) { v[j] = wp[j] * sv; ss += v[j] * v[j]; }
#pragma unroll
  for (int off = 32; off; off >>= 1) ss += __shfl_down(ss, off);
  __shared__ float red[2];
  if ((threadIdx.x & 63) == 0) red[threadIdx.x >> 6] = ss;
  __syncthreads();
  const float dem = rsqrtf(red[0] + red[1] + 1e-8f);
#pragma unroll
  for (int j = 0; j < 9; ++j) {
    __hip_bfloat16 h = __float2bfloat16(v[j] * dem);
    w_ws[(((size_t)b * 9 + j) * 128 + cout) * 128 + cin] =
        __builtin_bit_cast(unsigned short, h);
  }
}

// x[b][cin][y][x] fp32 -> xp[b][y][xcol 0..129][cin] bf16, xcol = x+1, guards zero.
__global__ void nhwc_kernel(const float* __restrict__ x, unsigned short* __restrict__ xp) {
  const int bid = blockIdx.x;
  const int b = bid >> 7, y = bid & 127;
  const int tid = threadIdx.x;
  const float* xb = x + (size_t)b * 128 * 16384 + y * 128;  // + cin*16384 + xc
  unsigned short* ob = xp + (size_t)(b * 128 + y) * XPITCH;
#pragma unroll
  for (int it = 0; it < 8; ++it) {
    const int v = it * 256 + tid;
    const int g = v >> 7, xc = v & 127;  // cin group (of 8), x coordinate
    short8 pack;
#pragma unroll
    for (int j = 0; j < 8; ++j) {
      __hip_bfloat16 h = __float2bfloat16(xb[(size_t)(g * 8 + j) * 16384 + xc]);
      pack[j] = __builtin_bit_cast(short, h);
    }
    *(short8*)(ob + (xc + 1) * 128 + g * 8) = pack;
  }
  const int c = tid & 127;
  if (tid < 128) ob[c] = 0;              // xcol 0  (x = -1)
  else           ob[129 * 128 + c] = 0;  // xcol 129 (x = 128)
}

// one block per (b, y): out[b][0..127][y][0..127] = sum_{ky,kx,cin} w'*x
// 128x128 tile, 4 waves in 2x2, each wave 4x4 of 16x16x32 bf16 MFMA, BK=64.
__global__ __launch_bounds__(256, 3) void conv_kernel(const unsigned short* __restrict__ xp,
                                                      const unsigned short* __restrict__ wws,
                                                      float* __restrict__ out) {
  __shared__ unsigned short lA[128 * 64];
  __shared__ unsigned short lB[128 * 64];
  const int tid = threadIdx.x;
  // XCD-aware swizzle: HW assigns block i -> XCD (i % 8). Give XCD x the
  // contiguous (b,y) range [x*256, (x+1)*256): b = {2x,2x+1}, all y in order.
  // Adjacent-y input-row reuse (3 ky taps) then hits the SAME XCD's L2.
  const int bid = (blockIdx.x & 7) * 256 + (blockIdx.x >> 3);
  const int b = bid >> 7, y = bid & 127;
  const int lane = tid & 63, w = tid >> 6;
  const int wm = w & 1, wn = w >> 1;
  const int l15 = lane & 15, q = lane >> 4;

  f32x4 acc[4][4];
#pragma unroll
  for (int i = 0; i < 4; ++i)
#pragma unroll
    for (int t = 0; t < 4; ++t) acc[i][t] = (f32x4){0.f, 0.f, 0.f, 0.f};

  const unsigned short* xb = xp + (size_t)b * 128 * XPITCH;
  const unsigned short* wb = wws + (size_t)b * 9 * 128 * 128;

  // staging: thread covers LDS bytes p*4096 + tid*16 (lane-linear as required).
  // XOR swizzle applied on the GLOBAL side: physical 16B group at row m holds
  // logical group (g ^ (m&7)) -> breaks 128B-row-stride conflicts on ds_read_b128.
  const int mbase = tid >> 3;
  const int goff = (((tid & 7) ^ ((tid >> 3) & 7)) << 3);
  const int eoff = tid * 8;

  for (int j3 = 0; j3 < 9; ++j3) {
    const int ky = j3 / 3;
    const int kx = j3 - ky * 3;
    const int yy = y + ky - 1;
    if (yy < 0 || yy > 127) continue;  // uniform per block
    const unsigned short* Ab = wb + j3 * (128 * 128);
    const unsigned short* Bb = xb + yy * XPITCH + kx * 128;
    for (int c0 = 0; c0 < 128; c0 += 64) {
      __syncthreads();
#pragma unroll
      for (int p = 0; p < 4; ++p) {
        const int gofs = p * 4096 + mbase * 128 + c0 + goff;
        const int e = p * 2048 + eoff;
        async16(lA + e, Ab + gofs);
        async16(lB + e, Bb + gofs);
      }
      __syncthreads();
#pragma unroll
      for (int s = 0; s < 2; ++s) {
        const int axor = (((s * 4 + q) ^ (l15 & 7)) << 3);
        short8 af[4], bf[4];
#pragma unroll
        for (int i = 0; i < 4; ++i)
          af[i] = *(const short8*)(lA + (wm * 64 + i * 16 + l15) * 64 + axor);
#pragma unroll
        for (int t = 0; t < 4; ++t)
          bf[t] = *(const short8*)(lB + (wn * 64 + t * 16 + l15) * 64 + axor);
#pragma unroll
        for (int i = 0; i < 4; ++i)
#pragma unroll
          for (int t = 0; t < 4; ++t)
            acc[i][t] = __builtin_amdgcn_mfma_f32_16x16x32_bf16(af[i], bf[t], acc[i][t], 0, 0, 0);
      }
    }
  }

  // C/D layout: col(pixel) = lane&15, row(cout) = (lane>>4)*4 + reg
  float* ob = out + ((size_t)b * 128 * 128 + y) * 128;
#pragma unroll
  for (int i = 0; i < 4; ++i) {
    const int coutb = wm * 64 + i * 16 + q * 4;
#pragma unroll
    for (int r = 0; r < 4; ++r) {
      float* orow = ob + (size_t)(coutb + r) * (128 * 128);
#pragma unroll
      for (int t = 0; t < 4; ++t) orow[wn * 64 + t * 16 + l15] = acc[i][t][r];
    }
  }
}

extern "C" void kernel_launch(void* const* d_in, const int* in_sizes, int n_in,
                              void* d_out, int out_size, void* d_ws, size_t ws_size,
                              hipStream_t stream) {
  const float* x = (const float*)d_in[0];
  const float* style = (const float*)d_in[1];
  const float* weight = (const float*)d_in[2];
  const float* mod_w = (const float*)d_in[3];
  const float* mod_b = (const float*)d_in[4];
  float* out = (float*)d_out;

  char* ws = (char*)d_ws;
  float* s_ws = (float*)ws;                                // 8 KB
  unsigned short* w_ws = (unsigned short*)(ws + 8192);     // 4.7 MB
  unsigned short* xp = (unsigned short*)(ws + (8u << 20)); // 68 MB

  style_kernel<<<512, 256, 0, stream>>>(style, mod_w, mod_b, s_ws);
  modw_kernel<<<16 * 128, 128, 0, stream>>>(weight, s_ws, w_ws);
  nhwc_kernel<<<16 * 128, 256, 0, stream>>>(x, xp);
  conv_kernel<<<16 * 128, 256, 0, stream>>>(xp, w_ws, out);
}

// Round 3
// 317.883 us; speedup vs baseline: 1.1179x; 1.0395x over previous
//
#include <hip/hip_runtime.h>
#include <hip/hip_bf16.h>

// ModulatedConv2d (StyleGAN2): B=16, Cin=Cout=128, K=3, H=W=128, STYLE=512
// bf16 MFMA implicit GEMM per (b, y-row). M=cout(128), N=x(128), K=cin*9.
// R3: nhwc transpose rewritten as vectorized LDS-staged transpose
//     (float4 loads, 8B swizzled LDS, 16B coalesced stores).

typedef __attribute__((ext_vector_type(8))) short short8;
typedef __attribute__((ext_vector_type(4))) float f32x4;

#define XPITCH (130 * 128)
#define CONV_SCALE 0.029462782549439483f /* 1/sqrt(128*9) */
#define LIN_SCALE 0.04419417382415922f   /* 1/sqrt(512) */

__device__ __forceinline__ void async16(unsigned short* lds, const unsigned short* g) {
  __builtin_amdgcn_global_load_lds((const __attribute__((address_space(1))) void*)g,
                                   (__attribute__((address_space(3))) void*)lds, 16, 0, 0);
}

__device__ __forceinline__ unsigned int pack2bf(float a, float b) {
  unsigned short ha = __builtin_bit_cast(unsigned short, __float2bfloat16(a));
  unsigned short hb = __builtin_bit_cast(unsigned short, __float2bfloat16(b));
  return (unsigned int)ha | ((unsigned int)hb << 16);
}

// s[b][cin] = sum_d style[b,d] * mod_w[cin,d] * LIN_SCALE + mod_b[cin]
// one wave per (b,cin); lanes cover d with float4 (fully coalesced).
__global__ void style_kernel(const float* __restrict__ style, const float* __restrict__ mod_w,
                             const float* __restrict__ mod_b, float* __restrict__ s_ws) {
  const int gw = blockIdx.x * 4 + (threadIdx.x >> 6);  // global wave 0..2047
  const int b = gw >> 7, cin = gw & 127, lane = threadIdx.x & 63;
  const float4 s0 = *(const float4*)(style + (size_t)b * 512 + lane * 4);
  const float4 s1 = *(const float4*)(style + (size_t)b * 512 + 256 + lane * 4);
  const float4 w0 = *(const float4*)(mod_w + (size_t)cin * 512 + lane * 4);
  const float4 w1 = *(const float4*)(mod_w + (size_t)cin * 512 + 256 + lane * 4);
  float acc = s0.x * w0.x + s0.y * w0.y + s0.z * w0.z + s0.w * w0.w +
              s1.x * w1.x + s1.y * w1.y + s1.z * w1.z + s1.w * w1.w;
#pragma unroll
  for (int off = 32; off; off >>= 1) acc += __shfl_xor(acc, off);
  if (lane == 0) s_ws[b * 128 + cin] = acc * LIN_SCALE + mod_b[cin];
}

// one block per (b, cout): wmod = CONV_SCALE*weight*s ; demod = rsqrt(sum wmod^2 + 1e-8)
// write bf16 w_ws[b][ky*3+kx][cout][cin]  (cin fastest, for A-tile staging)
__global__ void modw_kernel(const float* __restrict__ weight, const float* __restrict__ s_ws,
                            unsigned short* __restrict__ w_ws) {
  const int bid = blockIdx.x;
  const int b = bid >> 7, cout = bid & 127;
  const int cin = threadIdx.x;
  const float sv = s_ws[b * 128 + cin] * CONV_SCALE;
  const float* wp = weight + ((size_t)cout * 128 + cin) * 9;
  float v[9];
  float ss = 0.f;
#pragma unroll
  for (int j = 0; j < 9; ++j) { v[j] = wp[j] * sv; ss += v[j] * v[j]; }
#pragma unroll
  for (int off = 32; off; off >>= 1) ss += __shfl_down(ss, off);
  __shared__ float red[2];
  if ((threadIdx.x & 63) == 0) red[threadIdx.x >> 6] = ss;
  __syncthreads();
  const float dem = rsqrtf(red[0] + red[1] + 1e-8f);
#pragma unroll
  for (int j = 0; j < 9; ++j) {
    __hip_bfloat16 h = __float2bfloat16(v[j] * dem);
    w_ws[(((size_t)b * 9 + j) * 128 + cout) * 128 + cin] =
        __builtin_bit_cast(unsigned short, h);
  }
}

// x[b][cin][y][x] fp32 -> xp[b][y][xcol 0..129][cin] bf16, xcol = x+1, guards zero.
// LDS-staged transpose: float4 coalesced reads, 4x4 in-register transpose,
// 8B swizzled LDS round-trip, 16B coalesced writes.
// LDS layout: T[xc][gp*4 ..], gp = g ^ (xc & 31), g = cin/4 (8B group).
// 8B/lane accesses: 4 lanes/bank = the b64 minimum -> conflict-free.
__global__ __launch_bounds__(256) void nhwc_kernel(const float* __restrict__ x,
                                                   unsigned short* __restrict__ xp) {
  __shared__ unsigned short T[128 * 128];  // 32 KB
  const int bid = blockIdx.x;
  const int b = bid >> 7, y = bid & 127;
  const int tid = threadIdx.x;
  const float* xb = x + (size_t)b * (128 * 16384) + y * 128;
  unsigned short* ob = xp + (size_t)(b * 128 + y) * XPITCH;

  const int xc4 = tid & 31;   // float4 index along x
  const int cing = tid >> 5;  // 0..7
#pragma unroll
  for (int r = 0; r < 4; ++r) {
    const int cin0 = r * 32 + cing * 4;
    const int g = cin0 >> 2;  // logical 8B-group = cin/4
    float4 f[4];
#pragma unroll
    for (int j = 0; j < 4; ++j)
      f[j] = *(const float4*)(xb + (size_t)(cin0 + j) * 16384 + xc4 * 4);
#pragma unroll
    for (int i = 0; i < 4; ++i) {
      const int xc = xc4 * 4 + i;
      const int gp = g ^ (xc & 31);  // swizzled physical group in row xc
      uint2 col;
      col.x = pack2bf(((const float*)&f[0])[i], ((const float*)&f[1])[i]);
      col.y = pack2bf(((const float*)&f[2])[i], ((const float*)&f[3])[i]);
      *(uint2*)(&T[xc * 128 + gp * 4]) = col;
    }
  }
  __syncthreads();
#pragma unroll
  for (int rr = 0; rr < 8; ++rr) {
    const int v = rr * 256 + tid;
    const int cg = v & 15;  // 16B output group: cin = cg*8
    const int xc = v >> 4;  // 0..127
    const int s5 = xc & 31;
    const int g0 = (cg * 2) ^ s5, g1 = (cg * 2 + 1) ^ s5;
    const uint2 a = *(const uint2*)(&T[xc * 128 + g0 * 4]);
    const uint2 c = *(const uint2*)(&T[xc * 128 + g1 * 4]);
    uint4 o;
    o.x = a.x; o.y = a.y; o.z = c.x; o.w = c.y;
    *(uint4*)(ob + (xc + 1) * 128 + cg * 8) = o;
  }
  // zero guards: xcol 0 (x=-1) and xcol 129 (x=128)
  const uint4 z = {0u, 0u, 0u, 0u};
  if (tid < 16) *(uint4*)(ob + tid * 8) = z;
  else if (tid < 32) *(uint4*)(ob + 129 * 128 + (tid - 16) * 8) = z;
}

// one block per (b, y): out[b][0..127][y][0..127] = sum_{ky,kx,cin} w'*x
// 128x128 tile, 4 waves in 2x2, each wave 4x4 of 16x16x32 bf16 MFMA, BK=64.
__global__ __launch_bounds__(256, 3) void conv_kernel(const unsigned short* __restrict__ xp,
                                                      const unsigned short* __restrict__ wws,
                                                      float* __restrict__ out) {
  __shared__ unsigned short lA[128 * 64];
  __shared__ unsigned short lB[128 * 64];
  const int tid = threadIdx.x;
  // XCD-aware swizzle: HW assigns block i -> XCD (i % 8). XCD x gets the
  // contiguous (b,y) range [x*256, (x+1)*256) so adjacent-y row reuse hits its L2.
  const int bid = (blockIdx.x & 7) * 256 + (blockIdx.x >> 3);
  const int b = bid >> 7, y = bid & 127;
  const int lane = tid & 63, w = tid >> 6;
  const int wm = w & 1, wn = w >> 1;
  const int l15 = lane & 15, q = lane >> 4;

  f32x4 acc[4][4];
#pragma unroll
  for (int i = 0; i < 4; ++i)
#pragma unroll
    for (int t = 0; t < 4; ++t) acc[i][t] = (f32x4){0.f, 0.f, 0.f, 0.f};

  const unsigned short* xb = xp + (size_t)b * 128 * XPITCH;
  const unsigned short* wb = wws + (size_t)b * 9 * 128 * 128;

  const int mbase = tid >> 3;
  const int goff = (((tid & 7) ^ ((tid >> 3) & 7)) << 3);
  const int eoff = tid * 8;

  for (int j3 = 0; j3 < 9; ++j3) {
    const int ky = j3 / 3;
    const int kx = j3 - ky * 3;
    const int yy = y + ky - 1;
    if (yy < 0 || yy > 127) continue;  // uniform per block
    const unsigned short* Ab = wb + j3 * (128 * 128);
    const unsigned short* Bb = xb + yy * XPITCH + kx * 128;
    for (int c0 = 0; c0 < 128; c0 += 64) {
      __syncthreads();
#pragma unroll
      for (int p = 0; p < 4; ++p) {
        const int gofs = p * 4096 + mbase * 128 + c0 + goff;
        const int e = p * 2048 + eoff;
        async16(lA + e, Ab + gofs);
        async16(lB + e, Bb + gofs);
      }
      __syncthreads();
#pragma unroll
      for (int s = 0; s < 2; ++s) {
        const int axor = (((s * 4 + q) ^ (l15 & 7)) << 3);
        short8 af[4], bf[4];
#pragma unroll
        for (int i = 0; i < 4; ++i)
          af[i] = *(const short8*)(lA + (wm * 64 + i * 16 + l15) * 64 + axor);
#pragma unroll
        for (int t = 0; t < 4; ++t)
          bf[t] = *(const short8*)(lB + (wn * 64 + t * 16 + l15) * 64 + axor);
#pragma unroll
        for (int i = 0; i < 4; ++i)
#pragma unroll
          for (int t = 0; t < 4; ++t)
            acc[i][t] = __builtin_amdgcn_mfma_f32_16x16x32_bf16(af[i], bf[t], acc[i][t], 0, 0, 0);
      }
    }
  }

  // C/D layout: col(pixel) = lane&15, row(cout) = (lane>>4)*4 + reg
  float* ob = out + ((size_t)b * 128 * 128 + y) * 128;
#pragma unroll
  for (int i = 0; i < 4; ++i) {
    const int coutb = wm * 64 + i * 16 + q * 4;
#pragma unroll
    for (int r = 0; r < 4; ++r) {
      float* orow = ob + (size_t)(coutb + r) * (128 * 128);
#pragma unroll
      for (int t = 0; t < 4; ++t) orow[wn * 64 + t * 16 + l15] = acc[i][t][r];
    }
  }
}

extern "C" void kernel_launch(void* const* d_in, const int* in_sizes, int n_in,
                              void* d_out, int out_size, void* d_ws, size_t ws_size,
                              hipStream_t stream) {
  const float* x = (const float*)d_in[0];
  const float* style = (const float*)d_in[1];
  const float* weight = (const float*)d_in[2];
  const float* mod_w = (const float*)d_in[3];
  const float* mod_b = (const float*)d_in[4];
  float* out = (float*)d_out;

  char* ws = (char*)d_ws;
  float* s_ws = (float*)ws;                                // 8 KB
  unsigned short* w_ws = (unsigned short*)(ws + 8192);     // 4.7 MB
  unsigned short* xp = (unsigned short*)(ws + (8u << 20)); // 68 MB

  style_kernel<<<512, 256, 0, stream>>>(style, mod_w, mod_b, s_ws);
  modw_kernel<<<16 * 128, 128, 0, stream>>>(weight, s_ws, w_ws);
  nhwc_kernel<<<16 * 128, 256, 0, stream>>>(x, xp);
  conv_kernel<<<16 * 128, 256, 0, stream>>>(xp, w_ws, out);
}